// Round 2
// baseline (33.558 us; speedup 1.0000x reference)
//
#include <hip/hip_runtime.h>

// out = P*noise + (1-P)*(latent @ W + b), P = prod_{t=1..steps} t/steps
// (closed form of the reference's affine scan)
//
// One wave per 4 consecutive rows. All 16 float4 loads issued up-front for
// MLP; 3-value compacted butterfly reduce (7 shuffles/row, results land on
// lanes 0/1/2 which are the storing lanes).

constexpr int D = 1024;

__global__ __launch_bounds__(256) void diff_init_kernel(
    const float* __restrict__ latent,   // [rows][1024]
    const float* __restrict__ W,        // [1024][3]
    const float* __restrict__ bvec,     // [3]
    const float* __restrict__ noise,    // [rows][3]
    const int*   __restrict__ steps_p,  // scalar
    float*       __restrict__ out,      // [rows][3]
    int rows)
{
    const int lane = threadIdx.x & 63;
    const int wave = blockIdx.x * (blockDim.x >> 6) + (threadIdx.x >> 6);
    const int row0 = wave * 4;
    if (row0 >= rows) return;

    const int steps = steps_p[0];
    float P = 1.0f;
    for (int t = steps; t >= 1; --t) P *= (float)t / (float)steps;
    const float Q = 1.0f - P;

    // Per-lane W fragment: lane covers float4-chunks idx = it*64+lane,
    // i.e. d in [idx*4, idx*4+4). 4 d's x 3 cols = 12 consecutive floats,
    // base offset idx*48 B -> 16B aligned -> three float4 loads.
    float w[4][12];
    #pragma unroll
    for (int it = 0; it < 4; ++it) {
        const float4* wp = (const float4*)(W + (size_t)(it * 64 + lane) * 12);
        float4 wa = wp[0], wb = wp[1], wc = wp[2];
        w[it][0] = wa.x; w[it][1]  = wa.y; w[it][2]  = wa.z; w[it][3]  = wa.w;
        w[it][4] = wb.x; w[it][5]  = wb.y; w[it][6]  = wb.z; w[it][7]  = wb.w;
        w[it][8] = wc.x; w[it][9]  = wc.y; w[it][10] = wc.z; w[it][11] = wc.w;
    }

    const float bb = (lane < 3) ? bvec[lane] : 0.0f;

    // ---- issue ALL latent loads up-front (16 KiB in flight per wave) ----
    float4 lv[4][4];
    const bool full = (row0 + 4 <= rows);
    if (full) {
        #pragma unroll
        for (int r = 0; r < 4; ++r) {
            const float4* lrow = (const float4*)(latent + (size_t)(row0 + r) * D);
            #pragma unroll
            for (int it = 0; it < 4; ++it) lv[r][it] = lrow[it * 64 + lane];
        }
    } else {
        #pragma unroll
        for (int r = 0; r < 4; ++r) {
            const float4* lrow = (const float4*)(latent + (size_t)(row0 + r) * D);
            #pragma unroll
            for (int it = 0; it < 4; ++it)
                lv[r][it] = (row0 + r < rows) ? lrow[it * 64 + lane]
                                              : float4{0.f, 0.f, 0.f, 0.f};
        }
    }

    // ---- FMA: 48 per row ----
    float acc[4][3];
    #pragma unroll
    for (int r = 0; r < 4; ++r) {
        float a0 = 0.f, a1 = 0.f, a2 = 0.f;
        #pragma unroll
        for (int it = 0; it < 4; ++it) {
            float4 lvv = lv[r][it];
            a0 = fmaf(lvv.x, w[it][0], a0);
            a1 = fmaf(lvv.x, w[it][1], a1);
            a2 = fmaf(lvv.x, w[it][2], a2);
            a0 = fmaf(lvv.y, w[it][3], a0);
            a1 = fmaf(lvv.y, w[it][4], a1);
            a2 = fmaf(lvv.y, w[it][5], a2);
            a0 = fmaf(lvv.z, w[it][6], a0);
            a1 = fmaf(lvv.z, w[it][7], a1);
            a2 = fmaf(lvv.z, w[it][8], a2);
            a0 = fmaf(lvv.w, w[it][9],  a0);
            a1 = fmaf(lvv.w, w[it][10], a1);
            a2 = fmaf(lvv.w, w[it][11], a2);
        }
        acc[r][0] = a0; acc[r][1] = a1; acc[r][2] = a2;
    }

    // ---- compacted 3-value reduce: 7 shuffles/row, totals on lanes 0/1/2 ----
    #pragma unroll
    for (int r = 0; r < 4; ++r) {
        float a = acc[r][0], b = acc[r][1], c = acc[r][2];
        // stage mask=1: merge (a,b) -> v (even lanes: a-pairsum, odd: b-pairsum)
        float keep = (lane & 1) ? b : a;
        float send = (lane & 1) ? a : b;
        float v = keep + __shfl_xor(send, 1, 64);
        c += __shfl_xor(c, 1, 64);
        // stage mask=2: merge (v,c) -> u (lane&3==0: a-quad, ==1: b-quad, >=2: c-quad)
        float keep2 = (lane & 2) ? c : v;
        float send2 = (lane & 2) ? v : c;
        float u = keep2 + __shfl_xor(send2, 2, 64);
        // plain butterfly over remaining bits (same lane&3 class)
        u += __shfl_xor(u, 4, 64);
        u += __shfl_xor(u, 8, 64);
        u += __shfl_xor(u, 16, 64);
        u += __shfl_xor(u, 32, 64);
        // lane k (k<3) now holds target[row][k]
        const int row = row0 + r;
        if (lane < 3 && row < rows) {
            const float nz = noise[(size_t)row * 3 + lane];
            out[(size_t)row * 3 + lane] = fmaf(P, nz, Q * (u + bb));
        }
    }
}

extern "C" void kernel_launch(void* const* d_in, const int* in_sizes, int n_in,
                              void* d_out, int out_size, void* d_ws, size_t ws_size,
                              hipStream_t stream) {
    const float* latent = (const float*)d_in[0];
    const float* W      = (const float*)d_in[1];
    const float* bvec   = (const float*)d_in[2];
    const float* noise  = (const float*)d_in[3];
    const int*   steps  = (const int*)d_in[4];
    float* out = (float*)d_out;

    const int rows   = in_sizes[0] / D;            // 4*8192 = 32768
    const int waves  = (rows + 3) / 4;             // 4 rows per wave
    const int blocks = (waves + 3) / 4;            // 4 waves per block
    diff_init_kernel<<<blocks, 256, 0, stream>>>(latent, W, bvec, noise, steps,
                                                 out, rows);
}

// Round 3
// 33.046 us; speedup vs baseline: 1.0155x; 1.0155x over previous
//
#include <hip/hip_runtime.h>

// out = P*noise + (1-P)*(latent @ W + b), P = prod_{t=1..steps} t/steps
// (closed form of the reference's affine scan; P ~ 3e-21 for steps=50)
//
// One wave per 4 consecutive rows (exact grid, no loop).
// - noise: ONE coalesced 48B load (lanes 0-11) hoisted to the top
// - out:   ONE coalesced 48B store (lanes 0-11) after 4 gather-shuffles
// - latent: 3 rows in flight (A/B/C buffers), software-pipelined
// - reduce: compacted 3-value butterfly, 7 shuffles/row, lands on lanes 0-2

typedef float f32x4 __attribute__((ext_vector_type(4)));

constexpr int D = 1024;

__global__ __launch_bounds__(256) void diff_init_kernel(
    const float* __restrict__ latent,   // [rows][1024]
    const float* __restrict__ W,        // [1024][3]
    const float* __restrict__ bvec,     // [3]
    const float* __restrict__ noise,    // [rows][3]
    const int*   __restrict__ steps_p,  // scalar
    float*       __restrict__ out,      // [rows][3]
    int rows)
{
    const int lane = threadIdx.x & 63;
    const int wave = blockIdx.x * (blockDim.x >> 6) + (threadIdx.x >> 6);
    const int row0 = wave * 4;
    if (row0 >= rows) return;

    const int steps = steps_p[0];
    float P = 1.0f;
    for (int t = steps; t >= 1; --t) P *= (float)t / (float)steps;
    const float Q = 1.0f - P;

    // ---- hoisted small loads: W fragments, bias, all 4 rows' noise ----
    // lane covers float4-chunks idx = it*64+lane (d in [idx*4, idx*4+4));
    // 4 d's x 3 cols = 12 consecutive floats at idx*48 B (16B aligned).
    float w[4][12];
    #pragma unroll
    for (int it = 0; it < 4; ++it) {
        const f32x4* wp = (const f32x4*)(W + (size_t)(it * 64 + lane) * 12);
        f32x4 wa = wp[0], wb = wp[1], wc = wp[2];
        w[it][0] = wa.x; w[it][1]  = wa.y; w[it][2]  = wa.z; w[it][3]  = wa.w;
        w[it][4] = wb.x; w[it][5]  = wb.y; w[it][6]  = wb.z; w[it][7]  = wb.w;
        w[it][8] = wc.x; w[it][9]  = wc.y; w[it][10] = wc.z; w[it][11] = wc.w;
    }
    const float bb = bvec[lane % 3];                 // lanes 0-11 use it
    float nz = 0.0f;
    if (lane < 12 && (size_t)row0 * 3 + lane < (size_t)rows * 3)
        nz = noise[(size_t)row0 * 3 + lane];         // one 48B coalesced load

    // row pointers (clamped for ragged tails; rows%4==0 in this problem)
    const f32x4* rp[4];
    #pragma unroll
    for (int r = 0; r < 4; ++r) {
        int rr = row0 + r; if (rr > rows - 1) rr = rows - 1;
        rp[r] = (const f32x4*)(latent + (size_t)rr * D);
    }

    // ---- per-row compute: 48 FMAs + compacted reduce (u on lanes 0-2) ----
    auto row_dot = [&](const f32x4 lv[4]) -> float {
        float a = 0.f, b = 0.f, c = 0.f;
        #pragma unroll
        for (int it = 0; it < 4; ++it) {
            f32x4 v4 = lv[it];
            a = fmaf(v4.x, w[it][0], a);
            b = fmaf(v4.x, w[it][1], b);
            c = fmaf(v4.x, w[it][2], c);
            a = fmaf(v4.y, w[it][3], a);
            b = fmaf(v4.y, w[it][4], b);
            c = fmaf(v4.y, w[it][5], c);
            a = fmaf(v4.z, w[it][6], a);
            b = fmaf(v4.z, w[it][7], b);
            c = fmaf(v4.z, w[it][8], c);
            a = fmaf(v4.w, w[it][9],  a);
            b = fmaf(v4.w, w[it][10], b);
            c = fmaf(v4.w, w[it][11], c);
        }
        // merge (a,b) at mask 1
        float keep = (lane & 1) ? b : a;
        float send = (lane & 1) ? a : b;
        float v = keep + __shfl_xor(send, 1, 64);
        c += __shfl_xor(c, 1, 64);
        // merge (v,c) at mask 2
        float keep2 = (lane & 2) ? c : v;
        float send2 = (lane & 2) ? v : c;
        float u = keep2 + __shfl_xor(send2, 2, 64);
        // butterfly within lane&3 classes
        u += __shfl_xor(u, 4, 64);
        u += __shfl_xor(u, 8, 64);
        u += __shfl_xor(u, 16, 64);
        u += __shfl_xor(u, 32, 64);
        return u;   // lanes ==0 mod4: a-total, ==1: b-total, ==2: c-total
    };

    // ---- software pipeline: 3 rows of latent in flight (A/B/C) ----
    f32x4 A[4], B[4], C[4];
    #pragma unroll
    for (int it = 0; it < 4; ++it) A[it] = rp[0][it * 64 + lane];
    #pragma unroll
    for (int it = 0; it < 4; ++it) B[it] = rp[1][it * 64 + lane];

    #pragma unroll
    for (int it = 0; it < 4; ++it) C[it] = rp[2][it * 64 + lane];
    const float u0 = row_dot(A);

    #pragma unroll
    for (int it = 0; it < 4; ++it) A[it] = rp[3][it * 64 + lane];
    const float u1 = row_dot(B);

    const float u2 = row_dot(C);
    const float u3 = row_dot(A);

    // ---- gather to lanes 0-11, one coalesced 48B store ----
    const int src = lane % 3;
    const float g0 = __shfl(u0, src, 64);
    const float g1 = __shfl(u1, src, 64);
    const float g2 = __shfl(u2, src, 64);
    const float g3 = __shfl(u3, src, 64);
    const int rsel = lane / 3;                       // 0..3 for lanes 0-11
    const float t = (rsel == 0) ? g0 : (rsel == 1) ? g1 : (rsel == 2) ? g2 : g3;
    if (lane < 12 && (size_t)row0 * 3 + lane < (size_t)rows * 3)
        out[(size_t)row0 * 3 + lane] = fmaf(P, nz, Q * (t + bb));
}

extern "C" void kernel_launch(void* const* d_in, const int* in_sizes, int n_in,
                              void* d_out, int out_size, void* d_ws, size_t ws_size,
                              hipStream_t stream) {
    const float* latent = (const float*)d_in[0];
    const float* W      = (const float*)d_in[1];
    const float* bvec   = (const float*)d_in[2];
    const float* noise  = (const float*)d_in[3];
    const int*   steps  = (const int*)d_in[4];
    float* out = (float*)d_out;

    const int rows   = in_sizes[0] / D;            // 4*8192 = 32768
    const int waves  = (rows + 3) / 4;             // 4 rows per wave
    const int blocks = (waves + 3) / 4;            // 4 waves per block -> 2048
    diff_init_kernel<<<blocks, 256, 0, stream>>>(latent, W, bvec, noise, steps,
                                                 out, rows);
}